// Round 15
// baseline (349.182 us; speedup 1.0000x reference)
//
#include <hip/hip_runtime.h>

typedef short short8 __attribute__((ext_vector_type(8)));
typedef float f32x4 __attribute__((ext_vector_type(4)));
typedef unsigned short ushort8_t __attribute__((ext_vector_type(8)));

#define O_CH 128
#define I_CH 128
#define HW 112
#define PLANE (HW * HW)         // 12544
#define NCOLR 114               // staged cols (112 + 2 halo)
#define NCOL2 130               // allocated col stride (114..129 = in-bounds garbage pad)
#define BUFB (3 * NCOL2 * 64)   // bytes per LDS buffer = 24960

__device__ __forceinline__ unsigned short f2bf(float f) {
  union { float f; unsigned u; } v; v.f = f;
  unsigned r = v.u + 0x7FFFu + ((v.u >> 16) & 1u);   // RNE (weights only)
  return (unsigned short)(r >> 16);
}

// one-instruction truncate-pack: [lo,hi] floats -> packed bf16 pair
__device__ __forceinline__ unsigned pktrunc(float lo, float hi) {
  union { float f; unsigned u; } a, b; a.f = lo; b.f = hi;
  return __builtin_amdgcn_perm(b.u, a.u, 0x07060302u);
}

__global__ void wsynth_kernel(const float* __restrict__ core,
                              const float* __restrict__ periph,
                              const float* __restrict__ thr,
                              const float* __restrict__ scale,
                              unsigned short* __restrict__ Wb) {
  int idx = blockIdx.x * blockDim.x + threadIdx.x;   // o*128 + i
  if (idx >= O_CH * I_CH) return;
  int o = idx >> 7;
  float c = core[idx];
  float s = scale[0];
  float g = 1.0f / (1.0f + __expf(-s * (fabsf(c) - thr[o])));
#pragma unroll
  for (int tap = 0; tap < 9; ++tap) {
    float p  = (tap == 4) ? 1.0f : periph[tap < 4 ? tap : tap - 1];
    float gg = (tap == 4) ? 1.0f : g;
    Wb[tap * (O_CH * I_CH) + idx] = f2bf(c * p * gg);   // layout [tap][o][i]
  }
}

__global__ __launch_bounds__(256, 3)
void conv_kernel(const float* __restrict__ X,
                 const unsigned short* __restrict__ Wb,
                 float* __restrict__ Out) {
  // 2 buffers x [row 0..2][col 0..129][32 ch] bf16; col-row = 64 B = 4 slots of 16 B.
  // Slot swizzle (R9-verified, 0 conflicts): slot' = chgrp ^ ((col>>1)&3)
  __shared__ unsigned short Xs[2 * 3 * NCOL2 * 32];   // 49,920 B -> 3 WGs/CU
  char* lds = (char*)Xs;

  // XCD-chunked swizzle: 3584 = 8 XCDs x 448 (R6-verified)
  const int bid = blockIdx.x;
  const int L = (bid & 7) * 448 + (bid >> 3);
  const int b = L / HW;
  const int y = L - b * HW;

  const int t   = threadIdx.x;
  const int wv  = t >> 6;              // wave 0..3
  const int l   = t & 63;
  const int ln  = l & 15;              // MFMA frag lane
  const int lk4 = l >> 4;              // k-slice 0..3
  const int mi  = wv >> 1;             // o-half: o in [mi*64, +64)
  const int ng  = wv & 1;              // col group: cols [ng*64, +64)
  const int cb  = ng * 64;             // column base for this wave

  // staging coords (R9-identical)
  const int c    = t & 127;            // staged col (input col + 1)
  const int chb  = (t >> 7) * 16;      // local channel base: 0 or 16
  const int icol = c - 1;
  const bool cok = (c < NCOLR);
  const int wxor = (c >> 1) & 3;       // verified conflict-free write swizzle

  f32x4 acc[4][4];                     // [m-frag][nf]
#pragma unroll
  for (int mt = 0; mt < 4; ++mt)
#pragma unroll
    for (int nf = 0; nf < 4; ++nf)
      acc[mt][nf] = (f32x4)0.0f;

  // per-wave weight base: 64 o's starting at mi*64
  const unsigned short* wbase = Wb + (mi * 64 + ln) * I_CH + lk4 * 8;

#define LOAD16(V, KCH, SUB)                                                     \
  {                                                                             \
    const int row_ = y + (SUB)-1;                                               \
    const bool ok_ = (row_ >= 0) && (row_ < HW) && (icol >= 0) && (icol < HW);  \
    const float* sp_ = X + ((size_t)(b * I_CH + (KCH) + chb) * HW + row_) * HW  \
                       + icol;                                                  \
    _Pragma("unroll") for (int j = 0; j < 16; ++j) V[j] = 0.0f;                 \
    if (ok_) {                                                                  \
      _Pragma("unroll") for (int j = 0; j < 16; ++j) V[j] = sp_[j * PLANE];     \
    }                                                                           \
  }

#define WRITE16(V, SUB, WB)                                                     \
  if (cok) {                                                                    \
    const int base_ = ((SUB)*NCOL2 + c) * 64;                                   \
    _Pragma("unroll") for (int q = 0; q < 2; ++q) {                             \
      union { ushort8_t s; unsigned u[4]; } pk_;                                \
      pk_.u[0] = pktrunc(V[q * 8 + 0], V[q * 8 + 1]);                           \
      pk_.u[1] = pktrunc(V[q * 8 + 2], V[q * 8 + 3]);                           \
      pk_.u[2] = pktrunc(V[q * 8 + 4], V[q * 8 + 5]);                           \
      pk_.u[3] = pktrunc(V[q * 8 + 6], V[q * 8 + 7]);                           \
      const int slot_ = ((chb >> 3) + q) ^ wxor;                                \
      *reinterpret_cast<ushort8_t*>((WB) + base_ + slot_ * 16) = pk_.s;         \
    }                                                                           \
  }

  // ALL 12 A-fragments for a sub-phase. MUST be issued before the staging loads;
  // the sched_barrier(0) after the call pins this against compiler sinking
  // (R14 lesson: without the pin, llvm sank these to their uses -> vmcnt(0)
  // drains of the staging queue at every dx -> R10's 313us pathology).
#define APLOADSUB(AF, SUB, K)                                                   \
  _Pragma("unroll") for (int dx = 0; dx < 3; ++dx) {                            \
    const unsigned short* wp_ = wbase + ((SUB)*3 + dx) * (O_CH * I_CH)          \
                              + (K)*32;                                         \
    AF[dx][0] = *reinterpret_cast<const short8*>(wp_);                          \
    AF[dx][1] = *reinterpret_cast<const short8*>(wp_ + 16 * I_CH);              \
    AF[dx][2] = *reinterpret_cast<const short8*>(wp_ + 32 * I_CH);              \
    AF[dx][3] = *reinterpret_cast<const short8*>(wp_ + 48 * I_CH);              \
  }

  // compute sub-phase: per dx 4 b128 B-reads, each feeding 4 MFMAs (uniform,
  // no divergence; ng1's nf3 computes in-bounds garbage, masked at store)
#define COMPUTE_SUB2R(SUB, RB, AF)                                              \
  _Pragma("unroll") for (int dx = 0; dx < 3; ++dx) {                            \
    const int q_ = cb + dx + ln;                                                \
    const int rslot_ = lk4 ^ ((q_ >> 1) & 3);   /* 16-col stride: invariant */  \
    const char* bp_ = (RB) + ((SUB)*NCOL2 + q_) * 64 + rslot_ * 16;             \
    _Pragma("unroll") for (int nf = 0; nf < 4; ++nf) {                          \
      short8 bb_ = *reinterpret_cast<const short8*>(bp_ + nf * 1024);           \
      acc[0][nf] = __builtin_amdgcn_mfma_f32_16x16x32_bf16(AF[dx][0], bb_, acc[0][nf], 0, 0, 0); \
      acc[1][nf] = __builtin_amdgcn_mfma_f32_16x16x32_bf16(AF[dx][1], bb_, acc[1][nf], 0, 0, 0); \
      acc[2][nf] = __builtin_amdgcn_mfma_f32_16x16x32_bf16(AF[dx][2], bb_, acc[2][nf], 0, 0, 0); \
      acc[3][nf] = __builtin_amdgcn_mfma_f32_16x16x32_bf16(AF[dx][3], bb_, acc[3][nf], 0, 0, 0); \
    }                                                                           \
  }

  // ---- prologue: stage chunk 0 into buffer 0 ----
  {
    float P0[16], P1[16], P2[16];
    LOAD16(P0, 0, 0)
    LOAD16(P1, 0, 1)
    LOAD16(P2, 0, 2)
    WRITE16(P0, 0, lds)
    WRITE16(P1, 1, lds)
    WRITE16(P2, 2, lds)
  }
  __syncthreads();

  // ---- main loop: 4 chunks, double-buffered, lag-1 writes;
  //      per sub: A-loads -> sched_barrier pin -> staging loads -> compute ----
#pragma unroll
  for (int k = 0; k < 4; ++k) {
    char* rbuf = lds + (k & 1) * BUFB;
    char* wbuf = lds + ((k & 1) ^ 1) * BUFB;
    float LA[16], LB[16];
    short8 AF[3][4];

    // sub 0
    APLOADSUB(AF, 0, k)
    __builtin_amdgcn_sched_barrier(0);
    if (k < 3) LOAD16(LA, (k + 1) * 32, 0)
    COMPUTE_SUB2R(0, rbuf, AF)

    // sub 1 (write sub0's staged row after compute: lag-1)
    APLOADSUB(AF, 1, k)
    __builtin_amdgcn_sched_barrier(0);
    if (k < 3) LOAD16(LB, (k + 1) * 32, 1)
    COMPUTE_SUB2R(1, rbuf, AF)
    if (k < 3) WRITE16(LA, 0, wbuf)

    // sub 2
    APLOADSUB(AF, 2, k)
    __builtin_amdgcn_sched_barrier(0);
    if (k < 3) LOAD16(LA, (k + 1) * 32, 2)
    COMPUTE_SUB2R(2, rbuf, AF)
    if (k < 3) {
      WRITE16(LB, 1, wbuf)
      WRITE16(LA, 2, wbuf)
      __syncthreads();
    }
  }

  // ---- epilogue: wave (mi,ng) owns o [mi*64,+64) x cols [cb, cb+64) ----
  // ng1 nf3 (cols 112..127) is garbage -> masked
  float* outp = Out + (size_t)b * O_CH * PLANE + (size_t)y * HW + cb;
#pragma unroll
  for (int mt = 0; mt < 4; ++mt) {
#pragma unroll
    for (int j = 0; j < 4; ++j) {
      const int o = mi * 64 + mt * 16 + lk4 * 4 + j;
      float* po = outp + (size_t)o * PLANE;
#pragma unroll
      for (int nf = 0; nf < 4; ++nf) {
        if (nf < 3 || ng == 0) {
          po[nf * 16 + ln] = acc[mt][nf][j];
        }
      }
    }
  }
}

extern "C" void kernel_launch(void* const* d_in, const int* in_sizes, int n_in,
                              void* d_out, int out_size, void* d_ws, size_t ws_size,
                              hipStream_t stream) {
  const float* x      = (const float*)d_in[0];
  const float* core   = (const float*)d_in[1];
  const float* periph = (const float*)d_in[2];
  const float* thr    = (const float*)d_in[3];
  const float* scale  = (const float*)d_in[4];
  unsigned short* Wb  = (unsigned short*)d_ws;   // 9*128*128*2 = 294,912 B

  wsynth_kernel<<<(O_CH * I_CH + 255) / 256, 256, 0, stream>>>(core, periph, thr, scale, Wb);

  const int grid = 32 * HW;   // one WG per (batch, output row) = 3584
  conv_kernel<<<grid, 256, 0, stream>>>(x, Wb, (float*)d_out);
}

// Round 16
// 224.347 us; speedup vs baseline: 1.5564x; 1.5564x over previous
//
#include <hip/hip_runtime.h>

typedef short short8 __attribute__((ext_vector_type(8)));
typedef float f32x4 __attribute__((ext_vector_type(4)));
typedef unsigned short ushort8_t __attribute__((ext_vector_type(8)));

#define O_CH 128
#define I_CH 128
#define HW 112
#define PLANE (HW * HW)        // 12544
#define NCOL 114               // 112 cols + 2 halo
#define BUFB (4 * NCOL * 64)   // bytes per LDS buffer: 4 rows * 114 cols * 32ch * 2B = 29184

__device__ __forceinline__ unsigned short f2bf(float f) {
  union { float f; unsigned u; } v; v.f = f;
  unsigned r = v.u + 0x7FFFu + ((v.u >> 16) & 1u);   // RNE (weights only)
  return (unsigned short)(r >> 16);
}

// one-instruction truncate-pack: [lo,hi] floats -> packed bf16 pair
__device__ __forceinline__ unsigned pktrunc(float lo, float hi) {
  union { float f; unsigned u; } a, b; a.f = lo; b.f = hi;
  return __builtin_amdgcn_perm(b.u, a.u, 0x07060302u);
}

__global__ void wsynth_kernel(const float* __restrict__ core,
                              const float* __restrict__ periph,
                              const float* __restrict__ thr,
                              const float* __restrict__ scale,
                              unsigned short* __restrict__ Wb) {
  int idx = blockIdx.x * blockDim.x + threadIdx.x;   // o*128 + i
  if (idx >= O_CH * I_CH) return;
  int o = idx >> 7;
  float c = core[idx];
  float s = scale[0];
  float g = 1.0f / (1.0f + __expf(-s * (fabsf(c) - thr[o])));
#pragma unroll
  for (int tap = 0; tap < 9; ++tap) {
    float p  = (tap == 4) ? 1.0f : periph[tap < 4 ? tap : tap - 1];
    float gg = (tap == 4) ? 1.0f : g;
    Wb[tap * (O_CH * I_CH) + idx] = f2bf(c * p * gg);   // layout [tap][o][i]
  }
}

// 2 output rows per WG: stage 4 input rows; each staged-row B-read feeds BOTH
// output rows (same data, different tap) -> per-output LDS reads/staging/barriers
// drop 33-50% vs the R9 single-row skeleton.
__global__ __launch_bounds__(256)
void conv_kernel(const float* __restrict__ X,
                 const unsigned short* __restrict__ Wb,
                 float* __restrict__ Out) {
  // 2 buffers x [row 0..3][col 0..113][32 ch] bf16; col-row = 64 B = 4 slots of 16 B.
  // Slot swizzle (R9-verified, 0 conflicts): slot' = chgrp ^ ((col>>1)&3)
  __shared__ unsigned short Xs[2 * 4 * NCOL * 32];   // 58,368 B -> 2 WGs/CU
  char* lds = (char*)Xs;

  // XCD-chunked swizzle: 1792 = 8 XCDs x 224 contiguous logical ids (bijective)
  const int bid = blockIdx.x;
  const int L = (bid & 7) * 224 + (bid >> 3);
  const int b = L / 56;
  const int yp = L - b * 56;
  const int y0 = yp * 2;               // output rows y0, y0+1

  const int t   = threadIdx.x;
  const int wv  = t >> 6;              // wave 0..3 -> o quarter (32 o's)
  const int l   = t & 63;
  const int ln  = l & 15;              // MFMA frag lane
  const int lk4 = l >> 4;              // k-slice 0..3

  // staging coords (R9-identical)
  const int c    = t & 127;            // staged col (input col + 1)
  const int chb  = (t >> 7) * 16;      // local channel base: 0 or 16
  const int icol = c - 1;
  const bool cok = (c < NCOL);
  const int wxor = (c >> 1) & 3;       // verified conflict-free write swizzle

  f32x4 acc[2][2][7];                  // [out-row][m-frag][nf] = 112 VGPR
#pragma unroll
  for (int r = 0; r < 2; ++r)
#pragma unroll
    for (int mr = 0; mr < 2; ++mr)
#pragma unroll
      for (int nf = 0; nf < 7; ++nf)
        acc[r][mr][nf] = (f32x4)0.0f;

  // per-wave weight base (32 o's at wv*32)
  const unsigned short* wbase = Wb + (wv * 32 + ln) * I_CH + lk4 * 8;

  // staged row S (0..3) = input row y0-1+S
#define LOAD16(V, KCH, S)                                                       \
  {                                                                             \
    const int row_ = y0 + (S)-1;                                                \
    const bool ok_ = (row_ >= 0) && (row_ < HW) && (icol >= 0) && (icol < HW);  \
    const float* sp_ = X + ((size_t)(b * I_CH + (KCH) + chb) * HW + row_) * HW  \
                       + icol;                                                  \
    _Pragma("unroll") for (int j = 0; j < 16; ++j) V[j] = 0.0f;                 \
    if (ok_) {                                                                  \
      _Pragma("unroll") for (int j = 0; j < 16; ++j) V[j] = sp_[j * PLANE];     \
    }                                                                           \
  }

#define WRITE16(V, S, WB)                                                       \
  if (cok) {                                                                    \
    const int base_ = ((S)*NCOL + c) * 64;                                      \
    _Pragma("unroll") for (int q = 0; q < 2; ++q) {                             \
      union { ushort8_t s; unsigned u[4]; } pk_;                                \
      pk_.u[0] = pktrunc(V[q * 8 + 0], V[q * 8 + 1]);                           \
      pk_.u[1] = pktrunc(V[q * 8 + 2], V[q * 8 + 3]);                           \
      pk_.u[2] = pktrunc(V[q * 8 + 4], V[q * 8 + 5]);                           \
      pk_.u[3] = pktrunc(V[q * 8 + 6], V[q * 8 + 7]);                           \
      const int slot_ = ((chb >> 3) + q) ^ wxor;                                \
      *reinterpret_cast<ushort8_t*>((WB) + base_ + slot_ * 16) = pk_.s;         \
    }                                                                           \
  }

  // A-frags for out-row0 at staged row S (tap = S*3+dx) / out-row1 (tap = (S-1)*3+dx)
#define APF(AF, TAPB, K)                                                        \
  _Pragma("unroll") for (int dx = 0; dx < 3; ++dx) {                            \
    const unsigned short* wp_ = wbase + ((TAPB) + dx) * (O_CH * I_CH) + (K)*32; \
    AF[dx][0] = *reinterpret_cast<const short8*>(wp_);                          \
    AF[dx][1] = *reinterpret_cast<const short8*>(wp_ + 16 * I_CH);              \
  }

  // compute contributions of staged row S: 21 B-reads; each feeds
  // row0 (if S<=2, tap S*3+dx) and row1 (if S>=1, tap (S-1)*3+dx)
#define COMPUTE_S(S, RB, A0F, A1F, USE0, USE1)                                  \
  _Pragma("unroll") for (int dx = 0; dx < 3; ++dx) {                            \
    const int q_ = dx + ln;                                                     \
    const int rslot_ = lk4 ^ ((q_ >> 1) & 3);   /* nf stride 16: invariant */   \
    const char* bp_ = (RB) + ((S)*NCOL + q_) * 64 + rslot_ * 16;                \
    _Pragma("unroll") for (int nf = 0; nf < 7; ++nf) {                          \
      short8 bb_ = *reinterpret_cast<const short8*>(bp_ + nf * 1024);           \
      if (USE0) {                                                               \
        acc[0][0][nf] = __builtin_amdgcn_mfma_f32_16x16x32_bf16(A0F[dx][0], bb_, acc[0][0][nf], 0, 0, 0); \
        acc[0][1][nf] = __builtin_amdgcn_mfma_f32_16x16x32_bf16(A0F[dx][1], bb_, acc[0][1][nf], 0, 0, 0); \
      }                                                                         \
      if (USE1) {                                                               \
        acc[1][0][nf] = __builtin_amdgcn_mfma_f32_16x16x32_bf16(A1F[dx][0], bb_, acc[1][0][nf], 0, 0, 0); \
        acc[1][1][nf] = __builtin_amdgcn_mfma_f32_16x16x32_bf16(A1F[dx][1], bb_, acc[1][1][nf], 0, 0, 0); \
      }                                                                         \
    }                                                                           \
  }

  // ---- prologue: stage chunk 0 (rows 0..3) into buffer 0 ----
  {
    float P0[16], P1[16];
    LOAD16(P0, 0, 0)
    LOAD16(P1, 0, 1)
    WRITE16(P0, 0, lds)
    WRITE16(P1, 1, lds)
    LOAD16(P0, 0, 2)
    LOAD16(P1, 0, 3)
    WRITE16(P0, 2, lds)
    WRITE16(P1, 3, lds)
  }
  __syncthreads();

  // ---- main loop: 4 chunks of 32 ch, double-buffered, 4 phases/chunk, 1 barrier ----
#pragma unroll
  for (int k = 0; k < 4; ++k) {
    char* rbuf = lds + (k & 1) * BUFB;
    char* wbuf = lds + ((k & 1) ^ 1) * BUFB;
    float LA[16], LB[16];
    short8 AF0[3][2], AF1[3][2];

    // phase 0: staged row 0 -> row0 only (taps 0..2)
    APF(AF0, 0, k)
    if (k < 3) LOAD16(LA, (k + 1) * 32, 0)
    COMPUTE_S(0, rbuf, AF0, AF1, 1, 0)

    // phase 1: staged row 1 -> row0 (taps 3..5) + row1 (taps 0..2)
    APF(AF0, 3, k)
    APF(AF1, 0, k)
    if (k < 3) LOAD16(LB, (k + 1) * 32, 1)
    COMPUTE_S(1, rbuf, AF0, AF1, 1, 1)
    if (k < 3) WRITE16(LA, 0, wbuf)

    // phase 2: staged row 2 -> row0 (taps 6..8) + row1 (taps 3..5)
    APF(AF0, 6, k)
    APF(AF1, 3, k)
    if (k < 3) LOAD16(LA, (k + 1) * 32, 2)
    COMPUTE_S(2, rbuf, AF0, AF1, 1, 1)
    if (k < 3) WRITE16(LB, 1, wbuf)

    // phase 3: staged row 3 -> row1 only (taps 6..8)
    APF(AF1, 6, k)
    if (k < 3) LOAD16(LB, (k + 1) * 32, 3)
    COMPUTE_S(3, rbuf, AF0, AF1, 0, 1)
    if (k < 3) {
      WRITE16(LA, 2, wbuf)
      WRITE16(LB, 3, wbuf)
      __syncthreads();
    }
  }

  // ---- epilogue: C/D map col=lane&15, row=(lane>>4)*4+j; 2 output rows ----
  const int obase = wv * 32 + lk4 * 4;
#pragma unroll
  for (int r = 0; r < 2; ++r) {
    float* outp = Out + (size_t)b * O_CH * PLANE + (size_t)(y0 + r) * HW;
#pragma unroll
    for (int mr = 0; mr < 2; ++mr) {
#pragma unroll
      for (int j = 0; j < 4; ++j) {
        const int o = obase + mr * 16 + j;
        float* po = outp + (size_t)o * PLANE;
#pragma unroll
        for (int nf = 0; nf < 7; ++nf) {
          po[nf * 16 + ln] = acc[r][mr][nf][j];
        }
      }
    }
  }
}

extern "C" void kernel_launch(void* const* d_in, const int* in_sizes, int n_in,
                              void* d_out, int out_size, void* d_ws, size_t ws_size,
                              hipStream_t stream) {
  const float* x      = (const float*)d_in[0];
  const float* core   = (const float*)d_in[1];
  const float* periph = (const float*)d_in[2];
  const float* thr    = (const float*)d_in[3];
  const float* scale  = (const float*)d_in[4];
  unsigned short* Wb  = (unsigned short*)d_ws;   // 9*128*128*2 = 294,912 B

  wsynth_kernel<<<(O_CH * I_CH + 255) / 256, 256, 0, stream>>>(core, periph, thr, scale, Wb);

  const int grid = 32 * (HW / 2);   // one WG per (batch, output-row pair) = 1792
  conv_kernel<<<grid, 256, 0, stream>>>(x, Wb, (float*)d_out);
}